// Round 17
// baseline (65.352 us; speedup 1.0000x reference)
//
#include <hip/hip_runtime.h>
#include <stdint.h>

#pragma clang fp contract(off)

typedef __attribute__((ext_vector_type(4))) int i32x4;
typedef __attribute__((ext_vector_type(16))) int i32x16;

#define B_    16
#define C_    128
#define HW_   56
#define L_    3136
#define CO_   128
#define F_    1152
#define M_    50176
#define NT_   784          // tiles (8 XCD * 98), 64 rows each

// ---- workspace layout (bytes) ----
#define OFF_PBMIN 0        // float[784]
#define OFF_PBMAX 4096     // float[784]
#define OFF_PRMIN 8192     // int[784]
#define OFF_PRMAX 12288    // int[784]
#define OFF_SW    16384    // float scale_w[128]
#define OFF_ZPW   16896    // int zp_w[128]
#define OFF_SXZX  17408    // float {sx, zx}
#define OFF_CNT   17536    // unsigned sync counters: 8 shards x 64B = 512
#define OFF_QS    18048    // int qsum[128]
#define OFF_QW    18560    // int8 qw2[j][ch][o][16] = 147456 -> ends 166016
#define OFF_QX    166016   // int8 qx_t[b][l][c] = 6422528 -> ends 6588544
#define OFF_S     6588544  // int S[b][3136] = 200704 -> ends 6789248
#define OFF_RES   6789248  // int res[50176][128] (FALLBACK PATH ONLY)

__device__ __forceinline__ int read_abit(const int* p) {
    int i = *p;
    if (i > 0 && i < 32) return i;
    float f = __int_as_float(i);
    int fi = (int)f;
    return (fi > 0 && fi < 32) ? fi : 8;
}

__device__ __forceinline__ int swz_tile(int blk) {
    return (blk & 7) * 98 + (blk >> 3);    // bijective on [0,784)
}

// ---- sharded grid barrier (coop co-residency; counters pre-zeroed) ----
__device__ __forceinline__ void gsync(char* ws) {
    unsigned* base = (unsigned*)(ws + OFF_CNT);
    __syncthreads();
    if (threadIdx.x == 0) {
        __threadfence();                    // release
        atomicAdd(&base[(blockIdx.x & 7) * 16], 1u);
    }
    if (threadIdx.x < 8) {
        while (__hip_atomic_load(&base[threadIdx.x * 16],
                                 __ATOMIC_RELAXED, __HIP_MEMORY_SCOPE_AGENT) < 98u)
            __builtin_amdgcn_s_sleep(2);
    }
    __threadfence();                        // acquire
    __syncthreads();
}

// ---- block-wide reductions (256 threads) ----
__device__ __forceinline__ void block_fminmax(float& mn, float& mx, float* sred) {
    for (int m = 32; m; m >>= 1) {
        mn = fminf(mn, __shfl_xor(mn, m));
        mx = fmaxf(mx, __shfl_xor(mx, m));
    }
    int w = threadIdx.x >> 6;
    if ((threadIdx.x & 63) == 0) { sred[w] = mn; sred[4 + w] = mx; }
    __syncthreads();
    mn = fminf(fminf(sred[0], sred[1]), fminf(sred[2], sred[3]));
    mx = fmaxf(fmaxf(sred[4], sred[5]), fmaxf(sred[6], sred[7]));
    __syncthreads();
}
__device__ __forceinline__ void block_iminmax(int& mn, int& mx, int* ired) {
    for (int m = 32; m; m >>= 1) {
        mn = min(mn, __shfl_xor(mn, m));
        mx = max(mx, __shfl_xor(mx, m));
    }
    int w = threadIdx.x >> 6;
    if ((threadIdx.x & 63) == 0) { ired[w] = mn; ired[4 + w] = mx; }
    __syncthreads();
    mn = min(min(ired[0], ired[1]), min(ired[2], ired[3]));
    mx = max(max(ired[4], ired[5]), max(ired[6], ired[7]));
    __syncthreads();
}
__device__ __forceinline__ int block_isum(int v, int* ired) {
    for (int m = 32; m; m >>= 1) v += __shfl_xor(v, m);
    int w = threadIdx.x >> 6;
    if ((threadIdx.x & 63) == 0) ired[w] = v;
    __syncthreads();
    v = ired[0] + ired[1] + ired[2] + ired[3];
    __syncthreads();
    return v;
}

// ====== kA: blocks 0..783 x-minmax partials; 784..911 weight quant ======
__global__ __launch_bounds__(256) void kA(const float4* __restrict__ x4,
                                          const float* __restrict__ wgt,
                                          char* __restrict__ ws) {
    __shared__ float sred[8];
    __shared__ int ired[8];
    int blk = blockIdx.x;
    if (blk < NT_) {
        float mn = 0.0f, mx = 0.0f;    // padding zeros included
        int base = blk * blockDim.x + threadIdx.x;
        int stride = NT_ * 256;
        #pragma unroll
        for (int k = 0; k < 8; ++k) {
            float4 v = x4[base + k * stride];
            mn = fminf(mn, fminf(fminf(v.x, v.y), fminf(v.z, v.w)));
            mx = fmaxf(mx, fmaxf(fmaxf(v.x, v.y), fmaxf(v.z, v.w)));
        }
        block_fminmax(mn, mx, sred);
        if (threadIdx.x == 0) {
            ((float*)(ws + OFF_PBMIN))[blk] = mn;
            ((float*)(ws + OFF_PBMAX))[blk] = mx;
        }
        return;
    }
    int o = blk - NT_;
    const float* wr = wgt + o * F_;
    float mn = 3.4e38f, mx = -3.4e38f;
    for (int f = threadIdx.x; f < F_; f += 256) {
        float v = wr[f];
        mn = fminf(mn, v); mx = fmaxf(mx, v);
    }
    block_fminmax(mn, mx, sred);
    float sw = 255.0f / fmaxf(mx - mn, 1e-8f);
    float zw = rintf(sw * mn) + 128.0f;
    signed char* qw = (signed char*)(ws + OFF_QW);
    int qsum = 0;
    for (int f = threadIdx.x; f < F_; f += 256) {
        float q = fminf(fmaxf(rintf(sw * wr[f] - zw), -128.0f), 127.0f);
        int qi = (int)q;
        qsum += qi;
        int c = f / 9, j = f - c * 9;
        qw[j * 16384 + (c >> 4) * 2048 + (o << 4) + (c & 15)] = (signed char)qi;
    }
    qsum = block_isum(qsum, ired);
    if (threadIdx.x == 0) {
        ((int*)(ws + OFF_QS))[o]  = qsum;
        ((int*)(ws + OFF_ZPW))[o] = (int)zw;
        ((float*)(ws + OFF_SW))[o] = sw;
    }
}

// ====== kP2x: per-block sx reduce + quantize x to qx_t + channel sums S ======
__global__ __launch_bounds__(256) void kP2x(const float* __restrict__ x,
                                            const int* __restrict__ abit_p,
                                            char* __restrict__ ws) {
    __shared__ float sred[8];
    __shared__ int ssum[4][64];
    float mn = 0.0f, mx = 0.0f;
    {
        const float* pbmin = (const float*)(ws + OFF_PBMIN);
        const float* pbmax = (const float*)(ws + OFF_PBMAX);
        for (int i = threadIdx.x; i < NT_; i += 256) {
            mn = fminf(mn, pbmin[i]);
            mx = fmaxf(mx, pbmax[i]);
        }
        block_fminmax(mn, mx, sred);
    }
    int abit = read_abit(abit_p);
    float nlv = (float)((1 << abit) - 1);
    float sx = nlv / fmaxf(mx - mn, 1e-8f);
    float zx = rintf(sx * mn) + (float)(1 << (abit - 1));
    if (threadIdx.x == 0 && blockIdx.x == 0) {
        ((float*)(ws + OFF_SXZX))[0] = sx;
        ((float*)(ws + OFF_SXZX))[1] = zx;
    }
    int nx = 1 << (abit - 1);
    float lo = -(float)nx, hif = (float)(nx - 1);
    signed char* qxt = (signed char*)(ws + OFF_QX);
    int gid = swz_tile(blockIdx.x);
    int b = gid / 49, lcq = gid - b * 49;
    int l0 = lcq * 64;
    int t = threadIdx.x, lane = t & 63, cgp = t >> 6;
    int l = l0 + lane;
    const float* xb = x + ((size_t)b * C_) * L_ + l;
    int4* dst = (int4*)(qxt + ((size_t)(b * L_ + l)) * 128);
    int psum = 0;
    #pragma unroll
    for (int ii = 0; ii < 2; ++ii) {
        int c16 = (cgp + 4 * ii) * 16;
        int wds[4];
        #pragma unroll
        for (int k = 0; k < 4; ++k) {
            int wv = 0;
            #pragma unroll
            for (int e = 0; e < 4; ++e) {
                int c = c16 + 4 * k + e;
                float v = xb[(size_t)c * L_];
                int qi = (int)fminf(fmaxf(rintf(sx * v - zx), lo), hif);
                psum += qi;
                wv |= (qi & 255) << (8 * e);
            }
            wds[k] = wv;
        }
        int4 vv; vv.x = wds[0]; vv.y = wds[1]; vv.z = wds[2]; vv.w = wds[3];
        dst[c16 >> 4] = vv;
    }
    ssum[cgp][lane] = psum;
    __syncthreads();
    if (cgp == 0) {
        int* S = (int*)(ws + OFF_S);
        S[b * L_ + l] = ssum[0][lane] + ssum[1][lane] + ssum[2][lane] + ssum[3][lane];
    }
}

// ---- P3: 64Mx128N MFMA int8 GEMM tile, accs in registers.
// A: per-lane direct global loads (L2-resident qxt), reg-prefetched 1 tap ahead.
// B: double-buffered 2x16KB LDS, write-late/load-early, ONE barrier per tap.
// pool: Bs0 0..16383 | Bs1 16384..32767 | sq 32768..33023 (S_s temp in Bs1)
template <bool WRITE_RES>
__device__ __forceinline__ void dev_p3(char* __restrict__ ws, char* pool, int* ired,
                                       const float* __restrict__ bias,
                                       int abit, float sx, float zx,
                                       i32x16& acc0, i32x16& acc1) {
    signed char* Bs0 = (signed char*)pool;
    signed char* Bs1 = (signed char*)(pool + 16384);
    int* S_s = (int*)(pool + 16384);         // temp, dead before Bs1 first written
    int* sq  = (int*)(pool + 32768);
    const signed char* qxt = (const signed char*)(ws + OFF_QX);
    const signed char* qw  = (const signed char*)(ws + OFF_QW);
    const int* Sg  = (const int*)(ws + OFF_S);
    const int* zpw = (const int*)(ws + OFF_ZPW);

    int t = threadIdx.x;
    int mg = swz_tile(blockIdx.x) * 64;
    int b = mg / L_, l0 = mg - b * L_;
    int prow0 = l0 / HW_;
    int nx = 1 << (abit - 1);
    int q0 = min(max(-(int)zx, -nx), nx - 1);
    int pw = (q0 & 255) * 0x01010101;
    i32x4 padv; padv[0] = pw; padv[1] = pw; padv[2] = pw; padv[3] = pw;
    int padS = C_ * q0;
    const signed char* qxtb = qxt + (size_t)b * L_ * 128;
    const int* Sb = Sg + b * L_;

    int lane = t & 63, w = t >> 6;
    int wm = (w >> 1) << 5, wn = (w & 1) << 6;
    int r = lane & 31, hi = lane >> 5;

    // per-lane A row geometry
    int lrow = l0 + wm + r;
    int oh = lrow / HW_, ow = lrow - oh * HW_;

    int4 br0, br1, br2, br3;
    #define P3_LOAD_B(J) do {                                                          \
        const int4* src = (const int4*)(qw + (J) * 16384);                             \
        br0 = src[t]; br1 = src[256 + t]; br2 = src[512 + t]; br3 = src[768 + t];      \
    } while (0)
    #define P3_LOAD_AF(J, DST) do {                                                    \
        int kh = (J) / 3 - 1, kw = (J) % 3 - 1;                                        \
        int ih = oh + kh, iw = ow + kw;                                                \
        bool vld = ((unsigned)ih < HW_) && ((unsigned)iw < HW_);                       \
        const signed char* ap = qxtb + (((ih * HW_ + iw) << 7) & 0x7FFFFFFF);          \
        _Pragma("unroll")                                                              \
        for (int kk = 0; kk < 4; ++kk)                                                 \
            DST[kk] = vld ? *(const i32x4*)(ap + (((kk << 1) + hi) << 4)) : padv;      \
    } while (0)

    // ---- prologue ----
    P3_LOAD_B(0);                       // B0 -> regs
    if (t < 232) {                      // S halo into Bs1 temp
        int ri = t / 58, c1 = t - ri * 58;
        int ih = prow0 - 1 + ri, iw = c1 - 1;
        S_s[t] = ((unsigned)ih < HW_ && (unsigned)iw < HW_) ? Sb[ih * HW_ + iw] : padS;
    }
    __syncthreads();
    if (t < 64) {                       // per-row 3x3 box sums
        int l = l0 + t;
        int oh2 = l / HW_, ow2 = l - oh2 * HW_;
        int ri = oh2 - prow0 + 1, ci = ow2 + 1;
        int s = 0;
        #pragma unroll
        for (int dr = -1; dr <= 1; ++dr)
            #pragma unroll
            for (int dc = -1; dc <= 1; ++dc)
                s += S_s[(ri + dr) * 58 + ci + dc];
        sq[t] = s;
    }
    {                                   // write Bs0 from regs; issue B1 loads
        int4* d = (int4*)Bs0;
        d[t] = br0; d[256 + t] = br1; d[512 + t] = br2; d[768 + t] = br3;
        P3_LOAD_B(1);
    }
    i32x4 afc[4], afn[4];
    P3_LOAD_AF(0, afc);
    __syncthreads();                    // sq + Bs0 ready; S_s dead

    #pragma unroll
    for (int i = 0; i < 16; ++i) { acc0[i] = 0; acc1[i] = 0; }

    // ---- K-loop: 9 taps, ONE barrier per tap ----
    #pragma unroll
    for (int j = 0; j < 9; ++j) {
        if (j < 8) {                    // write-late B(j+1); issue B(j+2) loads
            int4* d = (int4*)(((j + 1) & 1) ? Bs1 : Bs0);
            d[t] = br0; d[256 + t] = br1; d[512 + t] = br2; d[768 + t] = br3;
            if (j < 7) P3_LOAD_B(j + 2);
        }
        const signed char* Bc = (j & 1) ? Bs1 : Bs0;
        i32x4 bf0[4], bf1[4];
        #pragma unroll
        for (int kk = 0; kk < 4; ++kk) {
            int ch2 = (kk << 1) + hi;
            bf0[kk] = *(const i32x4*)&Bc[ch2 * 2048 + ((wn + r) << 4)];
            bf1[kk] = *(const i32x4*)&Bc[ch2 * 2048 + ((wn + 32 + r) << 4)];
        }
        if (j < 8) P3_LOAD_AF(j + 1, afn);   // A prefetch rides under MFMA
        #pragma unroll
        for (int kk = 0; kk < 4; ++kk) {
            acc0 = __builtin_amdgcn_mfma_i32_32x32x32_i8(afc[kk], bf0[kk], acc0, 0, 0, 0);
            acc1 = __builtin_amdgcn_mfma_i32_32x32x32_i8(afc[kk], bf1[kk], acc1, 0, 0, 0);
        }
        #pragma unroll
        for (int kk = 0; kk < 4; ++kk) afc[kk] = afn[kk];
        __syncthreads();                // RAW for Bs[(j+1)&1]; WAR via prev barrier
    }
    #undef P3_LOAD_B
    #undef P3_LOAD_AF

    // ---- epilogue: corrections in-register + block min/max partials ----
    int o0 = wn + r, o1 = wn + 32 + r;
    const int* qs = (const int*)(ws + OFF_QS);
    const float* swp = (const float*)(ws + OFF_SW);
    int zxi = (int)zx;
    int zw0 = zpw[o0], zw1 = zpw[o1];
    int c0 = zxi * qs[o0] + F_ * zw0 * zxi + (int)rintf(swp[o0] * sx * bias[o0]);
    int c1 = zxi * qs[o1] + F_ * zw1 * zxi + (int)rintf(swp[o1] * sx * bias[o1]);
    int lmin = INT32_MAX, lmax = INT32_MIN;
    int* resp = (int*)(ws + OFF_RES);
    #pragma unroll
    for (int g = 0; g < 16; ++g) {
        int row = wm + (g & 3) + ((g >> 2) << 3) + (hi << 2);
        int s = sq[row];
        int v0 = acc0[g] + zw0 * s + c0;
        int v1 = acc1[g] + zw1 * s + c1;
        acc0[g] = v0; acc1[g] = v1;
        lmin = min(lmin, min(v0, v1));
        lmax = max(lmax, max(v0, v1));
        if (WRITE_RES) {
            int m = mg + row;
            resp[m * CO_ + o0] = v0;
            resp[m * CO_ + o1] = v1;
        }
    }
    block_iminmax(lmin, lmax, ired);
    if (t == 0) {
        ((int*)(ws + OFF_PRMIN))[blockIdx.x] = lmin;
        ((int*)(ws + OFF_PRMAX))[blockIdx.x] = lmax;
    }
    __syncthreads();
}

__device__ __forceinline__ void dev_reduce_pr(const char* ws, int* ired,
                                              int& rmin, int& rmax) {
    const int* prmin = (const int*)(ws + OFF_PRMIN);
    const int* prmax = (const int*)(ws + OFF_PRMAX);
    int mn = INT32_MAX, mx = INT32_MIN;
    for (int i = threadIdx.x; i < NT_; i += 256) {
        mn = min(mn, prmin[i]);
        mx = max(mx, prmax[i]);
    }
    block_iminmax(mn, mx, ired);
    rmin = mn; rmax = mx;
}

// ========== kCoop: GEMM (accs in regs) -> gsync -> reduce -> P4 store ==========
__global__ __launch_bounds__(256, 4) void kCoop(const float* __restrict__ bias,
                                                const int* __restrict__ abit_p,
                                                char* __restrict__ ws,
                                                float* __restrict__ out) {
    __shared__ __align__(16) char pool[33280];
    __shared__ int ired[8];

    float sx = ((const float*)(ws + OFF_SXZX))[0];
    float zx = ((const float*)(ws + OFF_SXZX))[1];
    int abit = read_abit(abit_p);

    i32x16 acc0, acc1;
    dev_p3<false>(ws, pool, ired, bias, abit, sx, zx, acc0, acc1);
    gsync(ws);

    int rmin, rmax;
    dev_reduce_pr(ws, ired, rmin, rmax);

    // P4: requant + dequant from registers; transpose via LDS; store out
    const float* swp = (const float*)(ws + OFF_SW);
    int t = threadIdx.x;
    int mg = swz_tile(blockIdx.x) * 64;
    int b = mg / L_, l0 = mg - b * L_;
    int lane = t & 63, w = t >> 6;
    int wm = (w >> 1) << 5, wn = (w & 1) << 6;
    int r = lane & 31, hi = lane >> 5;
    int o0 = wn + r, o1 = wn + 32 + r;
    int nx = 1 << (abit - 1);
    float nlev = (float)((1 << abit) - 1);
    float sr = nlev / fmaxf((float)rmax - (float)rmin, 1e-8f);
    float zr = rintf(sr * (float)rmin) + (float)nx;
    float lo = -(float)nx, hiq = (float)(nx - 1);
    float swsx0 = swp[o0] * sx, swsx1 = swp[o1] * sx;
    float* tile = (float*)pool;        // [64][129] f32 = 33024 B
    #pragma unroll
    for (int g = 0; g < 16; ++g) {
        int row = wm + (g & 3) + ((g >> 2) << 3) + (hi << 2);
        float qa = fminf(fmaxf(rintf(sr * (float)acc0[g] - zr), lo), hiq);
        float qb = fminf(fmaxf(rintf(sr * (float)acc1[g] - zr), lo), hiq);
        tile[row * 129 + o0] = ((qa + zr) / sr) / swsx0;
        tile[row * 129 + o1] = ((qb + zr) / sr) / swsx1;
    }
    __syncthreads();
    #pragma unroll
    for (int i = 0; i < 8; ++i) {
        int o = (t >> 4) + i * 16;
        int l4 = (t & 15) * 4;
        float4 f;
        #pragma unroll
        for (int jj = 0; jj < 4; ++jj)
            ((float*)&f)[jj] = tile[(l4 + jj) * 129 + o];
        *(float4*)(out + ((size_t)(b * CO_ + o)) * L_ + l0 + l4) = f;
    }
}

// =================== fallback (non-cooperative) path ===================
__global__ __launch_bounds__(256, 4) void fbGEMM(const float* __restrict__ bias,
                                                 const int* __restrict__ abit_p,
                                                 char* __restrict__ ws) {
    __shared__ __align__(16) char pool[33280];
    __shared__ int ired[8];
    float sx = ((const float*)(ws + OFF_SXZX))[0];
    float zx = ((const float*)(ws + OFF_SXZX))[1];
    int abit = read_abit(abit_p);
    i32x16 acc0, acc1;
    dev_p3<true>(ws, pool, ired, bias, abit, sx, zx, acc0, acc1);
}

__global__ __launch_bounds__(256) void fbDEQ(const int* __restrict__ abit_p,
                                             char* __restrict__ ws,
                                             float* __restrict__ out) {
    __shared__ int tile[64 * 65];
    __shared__ int ired[8];
    float sxv = ((const float*)(ws + OFF_SXZX))[0];
    int abit = read_abit(abit_p);
    float nlv = (float)((1 << abit) - 1);
    int rmin, rmax;
    dev_reduce_pr(ws, ired, rmin, rmax);

    const int* res = (const int*)(ws + OFF_RES);
    const float* scale_w = (const float*)(ws + OFF_SW);
    int t = threadIdx.x;
    int bid = blockIdx.x;
    int lcq = bid % 49; int tmp2 = bid / 49; int ocq = tmp2 & 1; int b = tmp2 >> 1;
    int l0 = lcq * 64, o0 = ocq * 64;

    const int* resb = res + ((size_t)(b * L_ + l0)) * CO_ + o0;
    #pragma unroll
    for (int i = 0; i < 4; ++i) {
        int lr = (t >> 4) + i * 16;
        int oc4 = (t & 15) * 4;
        int4 v = *(const int4*)(resb + lr * CO_ + oc4);
        int* d = &tile[lr * 65 + oc4];
        d[0] = v.x; d[1] = v.y; d[2] = v.z; d[3] = v.w;
    }
    int nxq = 1 << (abit - 1);
    float sr = nlv / fmaxf((float)rmax - (float)rmin, 1e-8f);
    float zr = rintf(sr * (float)rmin) + (float)nxq;
    float lo = -(float)nxq, hiq = (float)(nxq - 1);
    __syncthreads();
    #pragma unroll
    for (int i = 0; i < 4; ++i) {
        int o = (t >> 4) + i * 16;
        int l4 = (t & 15) * 4;
        float swsx = scale_w[o0 + o] * sxv;
        float4 f;
        #pragma unroll
        for (int jj = 0; jj < 4; ++jj) {
            int rv = tile[(l4 + jj) * 65 + o];
            float q = fminf(fmaxf(rintf(sr * (float)rv - zr), lo), hiq);
            ((float*)&f)[jj] = ((q + zr) / sr) / swsx;
        }
        *(float4*)(out + ((size_t)(b * CO_ + o0 + o)) * L_ + l0 + l4) = f;
    }
}

// ---------------- launch ----------------

extern "C" void kernel_launch(void* const* d_in, const int* in_sizes, int n_in,
                              void* d_out, int out_size, void* d_ws, size_t ws_size,
                              hipStream_t stream) {
    const float* x      = (const float*)d_in[0];
    const float* weight = (const float*)d_in[1];
    const float* bias   = (const float*)d_in[2];
    const int*   abit   = (const int*)d_in[3];
    float* out = (float*)d_out;
    char* ws = (char*)d_ws;

    int dev = 0;
    hipGetDevice(&dev);
    int ncu = 0;
    hipDeviceGetAttribute(&ncu, hipDeviceAttributeMultiprocessorCount, dev);
    int nb = 0;
    hipOccupancyMaxActiveBlocksPerMultiprocessor(&nb, (const void*)kCoop, 256, 0);

    kA<<<NT_ + CO_, 256, 0, stream>>>((const float4*)x, weight, ws);
    kP2x<<<NT_, 256, 0, stream>>>(x, abit, ws);

    if (nb > 0 && (long)nb * (long)ncu >= NT_) {
        hipMemsetAsync(ws + OFF_CNT, 0, 512, stream);
        kCoop<<<NT_, 256, 0, stream>>>(bias, abit, ws, out);
    } else {
        fbGEMM<<<NT_, 256, 0, stream>>>(bias, abit, ws);
        fbDEQ<<<1568, 256, 0, stream>>>(abit, ws, out);
    }
}

// Round 18
// 54.152 us; speedup vs baseline: 1.2068x; 1.2068x over previous
//
#include <hip/hip_runtime.h>
#include <stdint.h>

#pragma clang fp contract(off)

typedef __attribute__((ext_vector_type(4))) int i32x4;
typedef __attribute__((ext_vector_type(16))) int i32x16;

#define B_    16
#define C_    128
#define HW_   56
#define L_    3136
#define CO_   128
#define F_    1152
#define M_    50176
#define NT_   784          // tiles (8 XCD * 98), 64 rows each

// ---- workspace layout (bytes) ----
#define OFF_PBMIN 0        // float[784]
#define OFF_PBMAX 4096     // float[784]
#define OFF_PRMIN 8192     // int[784]
#define OFF_PRMAX 12288    // int[784]
#define OFF_SW    16384    // float scale_w[128]
#define OFF_ZPW   16896    // int zp_w[128]
#define OFF_SXZX  17408    // float {sx, zx}
#define OFF_CNT   17536    // unsigned sync counters: 8 shards x 64B = 512
#define OFF_QS    18048    // int qsum[128]
#define OFF_QW    18560    // int8 qw2[j][ch][o][16] = 147456 -> ends 166016
#define OFF_QX    166016   // int8 qx_t[b][l][c] = 6422528 -> ends 6588544
#define OFF_S     6588544  // int S[b][3136] = 200704 -> ends 6789248
#define OFF_RES   6789248  // int res[50176][128] (FALLBACK PATH ONLY)

__device__ __forceinline__ int read_abit(const int* p) {
    int i = *p;
    if (i > 0 && i < 32) return i;
    float f = __int_as_float(i);
    int fi = (int)f;
    return (fi > 0 && fi < 32) ? fi : 8;
}

__device__ __forceinline__ int swz_tile(int blk) {
    return (blk & 7) * 98 + (blk >> 3);    // bijective on [0,784)
}

// ---- sharded grid barrier (relies on coop co-residency; counters pre-zeroed) ----
__device__ __forceinline__ void gsync(char* ws) {
    unsigned* base = (unsigned*)(ws + OFF_CNT);
    __syncthreads();
    if (threadIdx.x == 0) {
        __threadfence();                    // release
        atomicAdd(&base[(blockIdx.x & 7) * 16], 1u);
    }
    if (threadIdx.x < 8) {
        while (__hip_atomic_load(&base[threadIdx.x * 16],
                                 __ATOMIC_RELAXED, __HIP_MEMORY_SCOPE_AGENT) < 98u)
            __builtin_amdgcn_s_sleep(2);
    }
    __threadfence();                        // acquire
    __syncthreads();
}

// ---- block-wide reductions (256 threads) ----
__device__ __forceinline__ void block_fminmax(float& mn, float& mx, float* sred) {
    for (int m = 32; m; m >>= 1) {
        mn = fminf(mn, __shfl_xor(mn, m));
        mx = fmaxf(mx, __shfl_xor(mx, m));
    }
    int w = threadIdx.x >> 6;
    if ((threadIdx.x & 63) == 0) { sred[w] = mn; sred[4 + w] = mx; }
    __syncthreads();
    mn = fminf(fminf(sred[0], sred[1]), fminf(sred[2], sred[3]));
    mx = fmaxf(fmaxf(sred[4], sred[5]), fmaxf(sred[6], sred[7]));
    __syncthreads();
}
__device__ __forceinline__ void block_iminmax(int& mn, int& mx, int* ired) {
    for (int m = 32; m; m >>= 1) {
        mn = min(mn, __shfl_xor(mn, m));
        mx = max(mx, __shfl_xor(mx, m));
    }
    int w = threadIdx.x >> 6;
    if ((threadIdx.x & 63) == 0) { ired[w] = mn; ired[4 + w] = mx; }
    __syncthreads();
    mn = min(min(ired[0], ired[1]), min(ired[2], ired[3]));
    mx = max(max(ired[4], ired[5]), max(ired[6], ired[7]));
    __syncthreads();
}
__device__ __forceinline__ int block_isum(int v, int* ired) {
    for (int m = 32; m; m >>= 1) v += __shfl_xor(v, m);
    int w = threadIdx.x >> 6;
    if ((threadIdx.x & 63) == 0) ired[w] = v;
    __syncthreads();
    v = ired[0] + ired[1] + ired[2] + ired[3];
    __syncthreads();
    return v;
}

// ====== kA: blocks 0..783 x-minmax partials; 784..911 weight quant ======
__global__ __launch_bounds__(256) void kA(const float4* __restrict__ x4,
                                          const float* __restrict__ wgt,
                                          char* __restrict__ ws) {
    __shared__ float sred[8];
    __shared__ int ired[8];
    int blk = blockIdx.x;
    if (blk < NT_) {
        float mn = 0.0f, mx = 0.0f;    // padding zeros included
        int base = blk * blockDim.x + threadIdx.x;
        int stride = NT_ * 256;
        #pragma unroll
        for (int k = 0; k < 8; ++k) {
            float4 v = x4[base + k * stride];
            mn = fminf(mn, fminf(fminf(v.x, v.y), fminf(v.z, v.w)));
            mx = fmaxf(mx, fmaxf(fmaxf(v.x, v.y), fmaxf(v.z, v.w)));
        }
        block_fminmax(mn, mx, sred);
        if (threadIdx.x == 0) {
            ((float*)(ws + OFF_PBMIN))[blk] = mn;
            ((float*)(ws + OFF_PBMAX))[blk] = mx;
        }
        return;
    }
    // weight quant (sx-independent): qw2[j][ch][o][16] pack + qsum/zpw/sw
    int o = blk - NT_;
    const float* wr = wgt + o * F_;
    float mn = 3.4e38f, mx = -3.4e38f;
    for (int f = threadIdx.x; f < F_; f += 256) {
        float v = wr[f];
        mn = fminf(mn, v); mx = fmaxf(mx, v);
    }
    block_fminmax(mn, mx, sred);
    float sw = 255.0f / fmaxf(mx - mn, 1e-8f);
    float zw = rintf(sw * mn) + 128.0f;
    signed char* qw = (signed char*)(ws + OFF_QW);
    int qsum = 0;
    for (int f = threadIdx.x; f < F_; f += 256) {
        float q = fminf(fmaxf(rintf(sw * wr[f] - zw), -128.0f), 127.0f);
        int qi = (int)q;
        qsum += qi;
        int c = f / 9, j = f - c * 9;
        qw[j * 16384 + (c >> 4) * 2048 + (o << 4) + (c & 15)] = (signed char)qi;
    }
    qsum = block_isum(qsum, ired);
    if (threadIdx.x == 0) {
        ((int*)(ws + OFF_QS))[o]  = qsum;
        ((int*)(ws + OFF_ZPW))[o] = (int)zw;
        ((float*)(ws + OFF_SW))[o] = sw;
    }
}

// ====== kP2x: per-block sx reduce + quantize x to qx_t + channel sums S ======
__global__ __launch_bounds__(256) void kP2x(const float* __restrict__ x,
                                            const int* __restrict__ abit_p,
                                            char* __restrict__ ws) {
    __shared__ float sred[8];
    __shared__ int ssum[4][64];
    // redundant per-block reduce of partials (6 KB, L2-hit) -> identical sx/zx
    float mn = 0.0f, mx = 0.0f;
    {
        const float* pbmin = (const float*)(ws + OFF_PBMIN);
        const float* pbmax = (const float*)(ws + OFF_PBMAX);
        for (int i = threadIdx.x; i < NT_; i += 256) {
            mn = fminf(mn, pbmin[i]);
            mx = fmaxf(mx, pbmax[i]);
        }
        block_fminmax(mn, mx, sred);
    }
    int abit = read_abit(abit_p);
    float nlv = (float)((1 << abit) - 1);
    float sx = nlv / fmaxf(mx - mn, 1e-8f);
    float zx = rintf(sx * mn) + (float)(1 << (abit - 1));
    if (threadIdx.x == 0 && blockIdx.x == 0) {
        ((float*)(ws + OFF_SXZX))[0] = sx;
        ((float*)(ws + OFF_SXZX))[1] = zx;
    }
    int nx = 1 << (abit - 1);
    float lo = -(float)nx, hif = (float)(nx - 1);
    signed char* qxt = (signed char*)(ws + OFF_QX);
    int gid = swz_tile(blockIdx.x);
    int b = gid / 49, lcq = gid - b * 49;
    int l0 = lcq * 64;
    int t = threadIdx.x, lane = t & 63, cgp = t >> 6;
    int l = l0 + lane;
    const float* xb = x + ((size_t)b * C_) * L_ + l;
    int4* dst = (int4*)(qxt + ((size_t)(b * L_ + l)) * 128);
    int psum = 0;
    #pragma unroll
    for (int ii = 0; ii < 2; ++ii) {
        int c16 = (cgp + 4 * ii) * 16;
        int wds[4];
        #pragma unroll
        for (int k = 0; k < 4; ++k) {
            int wv = 0;
            #pragma unroll
            for (int e = 0; e < 4; ++e) {
                int c = c16 + 4 * k + e;
                float v = xb[(size_t)c * L_];
                int qi = (int)fminf(fmaxf(rintf(sx * v - zx), lo), hif);
                psum += qi;
                wv |= (qi & 255) << (8 * e);
            }
            wds[k] = wv;
        }
        int4 vv; vv.x = wds[0]; vv.y = wds[1]; vv.z = wds[2]; vv.w = wds[3];
        dst[c16 >> 4] = vv;
    }
    ssum[cgp][lane] = psum;
    __syncthreads();
    if (cgp == 0) {
        int* S = (int*)(ws + OFF_S);
        S[b * L_ + l] = ssum[0][lane] + ssum[1][lane] + ssum[2][lane] + ssum[3][lane];
    }
}

// ---- P3: 64Mx128N MFMA int8 GEMM tile; corrected accs stay in registers ----
// pool layout: As 0..8191 | Bs 8192..24575 | S_s 24576..25503 | sq 25504..25759
template <bool WRITE_RES>
__device__ __forceinline__ void dev_p3(char* __restrict__ ws, char* pool, int* ired,
                                       const float* __restrict__ bias,
                                       int abit, float sx, float zx,
                                       i32x16& acc0, i32x16& acc1) {
    signed char* As = (signed char*)pool;
    signed char* Bs = (signed char*)(pool + 8192);
    int* S_s = (int*)(pool + 24576);
    int* sq  = (int*)(pool + 25504);
    const signed char* qxt = (const signed char*)(ws + OFF_QX);
    const signed char* qw  = (const signed char*)(ws + OFF_QW);
    const int* Sg  = (const int*)(ws + OFF_S);
    const int* zpw = (const int*)(ws + OFF_ZPW);

    int t = threadIdx.x;
    int mg = swz_tile(blockIdx.x) * 64;
    int b = mg / L_, l0 = mg - b * L_;
    int prow0 = l0 / HW_;
    int nx = 1 << (abit - 1);
    int q0 = min(max(-(int)zx, -nx), nx - 1);
    int pw = (q0 & 255) * 0x01010101;
    int4 pad4; pad4.x = pw; pad4.y = pw; pad4.z = pw; pad4.w = pw;
    int padS = C_ * q0;
    const signed char* qxtb = qxt + (size_t)b * L_ * 128;
    const int* Sb = Sg + b * L_;

    int chA = t & 7, rowA0 = t >> 3, rowA1 = rowA0 + 32;
    int li0 = l0 + rowA0, li1 = l0 + rowA1;
    int oh0 = li0 / HW_, ow0 = li0 - oh0 * HW_;
    int oh1 = li1 / HW_, ow1 = li1 - oh1 * HW_;

    int4 a0, a1, br0, br1, br2, br3;
    #define P3_LOAD_A(J) do {                                                          \
        int kh = (J) / 3 - 1, kw = (J) % 3 - 1;                                        \
        int ih = oh0 + kh, iw = ow0 + kw;                                              \
        a0 = ((unsigned)ih < HW_ && (unsigned)iw < HW_)                                \
             ? *(const int4*)(qxtb + ((ih * HW_ + iw) << 7) + (chA << 4)) : pad4;      \
        ih = oh1 + kh; iw = ow1 + kw;                                                  \
        a1 = ((unsigned)ih < HW_ && (unsigned)iw < HW_)                                \
             ? *(const int4*)(qxtb + ((ih * HW_ + iw) << 7) + (chA << 4)) : pad4;      \
    } while (0)
    #define P3_LOAD_B(J) do {                                                          \
        const int4* src = (const int4*)(qw + (J) * 16384);                             \
        br0 = src[t]; br1 = src[256 + t]; br2 = src[512 + t]; br3 = src[768 + t];      \
    } while (0)

    P3_LOAD_A(0); P3_LOAD_B(0);
    if (t < 232) {
        int ri = t / 58, c1 = t - ri * 58;
        int ih = prow0 - 1 + ri, iw = c1 - 1;
        S_s[t] = ((unsigned)ih < HW_ && (unsigned)iw < HW_) ? Sb[ih * HW_ + iw] : padS;
    }
    __syncthreads();
    if (t < 64) {
        int l = l0 + t;
        int oh = l / HW_, ow = l - oh * HW_;
        int ri = oh - prow0 + 1, ci = ow + 1;
        int s = 0;
        #pragma unroll
        for (int dr = -1; dr <= 1; ++dr)
            #pragma unroll
            for (int dc = -1; dc <= 1; ++dc)
                s += S_s[(ri + dr) * 58 + ci + dc];
        sq[t] = s;
    }

    int lane = t & 63, w = t >> 6;
    int wm = (w >> 1) << 5, wn = (w & 1) << 6;
    int r = lane & 31, hi = lane >> 5;
    #pragma unroll
    for (int i = 0; i < 16; ++i) { acc0[i] = 0; acc1[i] = 0; }

    #pragma unroll
    for (int j = 0; j < 9; ++j) {
        if (j > 0) __syncthreads();            // WAR
        *(int4*)&As[(rowA0 << 7) + ((chA ^ (rowA0 & 7)) << 4)] = a0;
        *(int4*)&As[(rowA1 << 7) + ((chA ^ (rowA1 & 7)) << 4)] = a1;
        {
            int4* d = (int4*)Bs;
            d[t] = br0; d[256 + t] = br1; d[512 + t] = br2; d[768 + t] = br3;
        }
        if (j < 8) { P3_LOAD_A(j + 1); P3_LOAD_B(j + 1); }
        __syncthreads();                        // RAW
        i32x4 af[4], bf0[4], bf1[4];
        #pragma unroll
        for (int kk = 0; kk < 4; ++kk) {
            int ch2 = kk * 2 + hi, row = wm + r;
            af[kk]  = *(const i32x4*)&As[(row << 7) + ((ch2 ^ (row & 7)) << 4)];
            bf0[kk] = *(const i32x4*)&Bs[ch2 * 2048 + ((wn + r) << 4)];
            bf1[kk] = *(const i32x4*)&Bs[ch2 * 2048 + ((wn + 32 + r) << 4)];
        }
        #pragma unroll
        for (int kk = 0; kk < 4; ++kk) {
            acc0 = __builtin_amdgcn_mfma_i32_32x32x32_i8(af[kk], bf0[kk], acc0, 0, 0, 0);
            acc1 = __builtin_amdgcn_mfma_i32_32x32x32_i8(af[kk], bf1[kk], acc1, 0, 0, 0);
        }
    }
    #undef P3_LOAD_A
    #undef P3_LOAD_B

    int o0 = wn + r, o1 = wn + 32 + r;
    const int* qs = (const int*)(ws + OFF_QS);
    const float* swp = (const float*)(ws + OFF_SW);
    int zxi = (int)zx;
    int zw0 = zpw[o0], zw1 = zpw[o1];
    int c0 = zxi * qs[o0] + F_ * zw0 * zxi + (int)rintf(swp[o0] * sx * bias[o0]);
    int c1 = zxi * qs[o1] + F_ * zw1 * zxi + (int)rintf(swp[o1] * sx * bias[o1]);
    int lmin = INT32_MAX, lmax = INT32_MIN;
    int* resp = (int*)(ws + OFF_RES);
    #pragma unroll
    for (int g = 0; g < 16; ++g) {
        int row = wm + (g & 3) + ((g >> 2) << 3) + (hi << 2);
        int s = sq[row];
        int v0 = acc0[g] + zw0 * s + c0;
        int v1 = acc1[g] + zw1 * s + c1;
        acc0[g] = v0; acc1[g] = v1;
        lmin = min(lmin, min(v0, v1));
        lmax = max(lmax, max(v0, v1));
        if (WRITE_RES) {
            int m = mg + row;
            resp[m * CO_ + o0] = v0;
            resp[m * CO_ + o1] = v1;
        }
    }
    block_iminmax(lmin, lmax, ired);
    if (t == 0) {
        ((int*)(ws + OFF_PRMIN))[blockIdx.x] = lmin;
        ((int*)(ws + OFF_PRMAX))[blockIdx.x] = lmax;
    }
    __syncthreads();
}

__device__ __forceinline__ void dev_reduce_pr(const char* ws, int* ired,
                                              int& rmin, int& rmax) {
    const int* prmin = (const int*)(ws + OFF_PRMIN);
    const int* prmax = (const int*)(ws + OFF_PRMAX);
    int mn = INT32_MAX, mx = INT32_MIN;
    for (int i = threadIdx.x; i < NT_; i += 256) {
        mn = min(mn, prmin[i]);
        mx = max(mx, prmax[i]);
    }
    block_iminmax(mn, mx, ired);
    rmin = mn; rmax = mx;
}

// ========== kCoop: GEMM (accs in regs) -> gsync -> reduce -> P4 store ==========
__global__ __launch_bounds__(256, 4) void kCoop(const float* __restrict__ bias,
                                                const int* __restrict__ abit_p,
                                                char* __restrict__ ws,
                                                float* __restrict__ out) {
    __shared__ __align__(16) char pool[33280];
    __shared__ int ired[8];

    float sx = ((const float*)(ws + OFF_SXZX))[0];
    float zx = ((const float*)(ws + OFF_SXZX))[1];
    int abit = read_abit(abit_p);

    i32x16 acc0, acc1;
    dev_p3<false>(ws, pool, ired, bias, abit, sx, zx, acc0, acc1);
    gsync(ws);

    int rmin, rmax;
    dev_reduce_pr(ws, ired, rmin, rmax);

    // P4: requant + dequant from registers; transpose via LDS; store out
    const float* swp = (const float*)(ws + OFF_SW);
    int t = threadIdx.x;
    int mg = swz_tile(blockIdx.x) * 64;
    int b = mg / L_, l0 = mg - b * L_;
    int lane = t & 63, w = t >> 6;
    int wm = (w >> 1) << 5, wn = (w & 1) << 6;
    int r = lane & 31, hi = lane >> 5;
    int o0 = wn + r, o1 = wn + 32 + r;
    int nx = 1 << (abit - 1);
    float nlev = (float)((1 << abit) - 1);
    float sr = nlev / fmaxf((float)rmax - (float)rmin, 1e-8f);
    float zr = rintf(sr * (float)rmin) + (float)nx;
    float lo = -(float)nx, hiq = (float)(nx - 1);
    float swsx0 = swp[o0] * sx, swsx1 = swp[o1] * sx;
    float* tile = (float*)pool;        // [64][129] f32 = 33024 B
    #pragma unroll
    for (int g = 0; g < 16; ++g) {
        int row = wm + (g & 3) + ((g >> 2) << 3) + (hi << 2);
        float qa = fminf(fmaxf(rintf(sr * (float)acc0[g] - zr), lo), hiq);
        float qb = fminf(fmaxf(rintf(sr * (float)acc1[g] - zr), lo), hiq);
        tile[row * 129 + o0] = ((qa + zr) / sr) / swsx0;
        tile[row * 129 + o1] = ((qb + zr) / sr) / swsx1;
    }
    __syncthreads();
    #pragma unroll
    for (int i = 0; i < 8; ++i) {
        int o = (t >> 4) + i * 16;
        int l4 = (t & 15) * 4;
        float4 f;
        #pragma unroll
        for (int jj = 0; jj < 4; ++jj)
            ((float*)&f)[jj] = tile[(l4 + jj) * 129 + o];
        *(float4*)(out + ((size_t)(b * CO_ + o)) * L_ + l0 + l4) = f;
    }
}

// =================== fallback (non-cooperative) path ===================
__global__ __launch_bounds__(256, 4) void fbGEMM(const float* __restrict__ bias,
                                                 const int* __restrict__ abit_p,
                                                 char* __restrict__ ws) {
    __shared__ __align__(16) char pool[25760];
    __shared__ int ired[8];
    float sx = ((const float*)(ws + OFF_SXZX))[0];
    float zx = ((const float*)(ws + OFF_SXZX))[1];
    int abit = read_abit(abit_p);
    i32x16 acc0, acc1;
    dev_p3<true>(ws, pool, ired, bias, abit, sx, zx, acc0, acc1);
}

__global__ __launch_bounds__(256) void fbDEQ(const int* __restrict__ abit_p,
                                             char* __restrict__ ws,
                                             float* __restrict__ out) {
    __shared__ int tile[64 * 65];
    __shared__ int ired[8];
    float sxv = ((const float*)(ws + OFF_SXZX))[0];
    int abit = read_abit(abit_p);
    float nlv = (float)((1 << abit) - 1);
    int rmin, rmax;
    dev_reduce_pr(ws, ired, rmin, rmax);

    const int* res = (const int*)(ws + OFF_RES);
    const float* scale_w = (const float*)(ws + OFF_SW);
    int t = threadIdx.x;
    int bid = blockIdx.x;
    int lcq = bid % 49; int tmp2 = bid / 49; int ocq = tmp2 & 1; int b = tmp2 >> 1;
    int l0 = lcq * 64, o0 = ocq * 64;

    const int* resb = res + ((size_t)(b * L_ + l0)) * CO_ + o0;
    #pragma unroll
    for (int i = 0; i < 4; ++i) {
        int lr = (t >> 4) + i * 16;
        int oc4 = (t & 15) * 4;
        int4 v = *(const int4*)(resb + lr * CO_ + oc4);
        int* d = &tile[lr * 65 + oc4];
        d[0] = v.x; d[1] = v.y; d[2] = v.z; d[3] = v.w;
    }
    int nxq = 1 << (abit - 1);
    float sr = nlv / fmaxf((float)rmax - (float)rmin, 1e-8f);
    float zr = rintf(sr * (float)rmin) + (float)nxq;
    float lo = -(float)nxq, hiq = (float)(nxq - 1);
    __syncthreads();
    #pragma unroll
    for (int i = 0; i < 4; ++i) {
        int o = (t >> 4) + i * 16;
        int l4 = (t & 15) * 4;
        float swsx = scale_w[o0 + o] * sxv;
        float4 f;
        #pragma unroll
        for (int jj = 0; jj < 4; ++jj) {
            int rv = tile[(l4 + jj) * 65 + o];
            float q = fminf(fmaxf(rintf(sr * (float)rv - zr), lo), hiq);
            ((float*)&f)[jj] = ((q + zr) / sr) / swsx;
        }
        *(float4*)(out + ((size_t)(b * CO_ + o0 + o)) * L_ + l0 + l4) = f;
    }
}

// ---------------- launch ----------------

extern "C" void kernel_launch(void* const* d_in, const int* in_sizes, int n_in,
                              void* d_out, int out_size, void* d_ws, size_t ws_size,
                              hipStream_t stream) {
    const float* x      = (const float*)d_in[0];
    const float* weight = (const float*)d_in[1];
    const float* bias   = (const float*)d_in[2];
    const int*   abit   = (const int*)d_in[3];
    float* out = (float*)d_out;
    char* ws = (char*)d_ws;

    int dev = 0;
    hipGetDevice(&dev);
    int ncu = 0;
    hipDeviceGetAttribute(&ncu, hipDeviceAttributeMultiprocessorCount, dev);
    int nb = 0;
    hipOccupancyMaxActiveBlocksPerMultiprocessor(&nb, (const void*)kCoop, 256, 0);

    kA<<<NT_ + CO_, 256, 0, stream>>>((const float4*)x, weight, ws);
    kP2x<<<NT_, 256, 0, stream>>>(x, abit, ws);

    if (nb > 0 && (long)nb * (long)ncu >= NT_) {
        hipMemsetAsync(ws + OFF_CNT, 0, 512, stream);
        kCoop<<<NT_, 256, 0, stream>>>(bias, abit, ws, out);
    } else {
        fbGEMM<<<NT_, 256, 0, stream>>>(bias, abit, ws);
        fbDEQ<<<1568, 256, 0, stream>>>(abit, ws, out);
    }
}